// Round 12
// baseline (651.233 us; speedup 1.0000x reference)
//
#include <hip/hip_runtime.h>
#include <math.h>
#include <stdint.h>

// Problem dims (fixed by setup_inputs)
#define B_N 256
#define C_N 1152
#define I_N 8
#define N_N 10
#define D_N 16

constexpr int C_PER    = 24;             // c's per block
constexpr int C_CHUNKS = C_N / C_PER;    // 48
constexpr int STAGE_C  = 6;              // c's per W staging round
constexpr int N_STAGES = 4;
constexpr int BLOCK    = 256;
constexpr int NBLOCKS  = C_CHUNKS * 16;  // 768 = 3 blocks/CU needed; capacity 4 -> safe

typedef short v8s __attribute__((ext_vector_type(8)));
typedef float v4f __attribute__((ext_vector_type(4)));

// ---- LDS pool (bytes) ----
//   Ws  (short): [6c][10n][16d][8i] = 15360 @ 0
//   xs  (short): [24c][16b][8i]     =  6144 @ 15360   (staged ONCE, 3 passes)
//   vst (float): [16b][164]         = 10496 @ 21504
//   cfl (float): [6c][163]          =  3912 @ 32000
//   rz  (float): [6c][16b]          =   384 @ 35912
//   comb(float): [16b][164] ALIASES Ws @ 0
constexpr int POOL_BYTES = 36296;   // cap 163840/36864 = 4 blocks/CU > 3 needed

__device__ __forceinline__ uint32_t bf16_rne(float f) {
    uint32_t u = __float_as_uint(f);
    return (u + 0x7FFFu + ((u >> 16) & 1u)) >> 16;
}
__device__ __forceinline__ uint32_t pack2(float a, float b) {
    return bf16_rne(a) | (bf16_rne(b) << 16);
}
__device__ __forceinline__ float bf2f(short s) {
    return __uint_as_float(((uint32_t)(uint16_t)s) << 16);
}

// Manual grid barrier (single-use counters, zeroed by hipMemsetAsync each call).
// Device-scope atomics + threadfence per G16 (cross-XCD safe). All 768 blocks
// are co-resident (3/CU needed, 4/CU capacity), so the spin cannot deadlock.
__device__ __forceinline__ void gridbar(uint32_t* cnt, int idx) {
    __syncthreads();
    if (threadIdx.x == 0) {
        __threadfence();
        __hip_atomic_fetch_add(&cnt[idx], 1u, __ATOMIC_ACQ_REL, __HIP_MEMORY_SCOPE_AGENT);
        while (__hip_atomic_load(&cnt[idx], __ATOMIC_ACQUIRE, __HIP_MEMORY_SCOPE_AGENT)
               < (uint32_t)NBLOCKS) { }
    }
    __syncthreads();
}

// Single-dispatch fused routing: 3 passes + 3 reduce/squash, manual grid sync.
__global__ __launch_bounds__(BLOCK, 3)
void fused_routing(const float* __restrict__ x, const float* __restrict__ W,
                   uint32_t* __restrict__ bar, float* __restrict__ vg,
                   float* __restrict__ ps, float* __restrict__ out)
{
    __shared__ __align__(16) char pool[POOL_BYTES];
    short* Ws   = (short*)pool;
    short* xs   = (short*)(pool + 15360);
    float* vst  = (float*)(pool + 21504);
    float* cfl  = (float*)(pool + 32000);
    float* rz   = (float*)(pool + 35912);
    float* comb = (float*)pool;

    const int tid   = threadIdx.x;
    const int wv    = tid >> 6;
    const int lane  = tid & 63;
    const int b     = lane & 15;   // D-col / B-col; also A-row m (=d)
    const int quad  = lane >> 4;
    const int chunk = blockIdx.x;
    const int btile = blockIdx.y;
    const int flat  = chunk + btile * C_CHUNKS;   // 0..767
    const int gb0   = btile * 16;
    const int c0    = chunk * C_PER;

    // ---- stage x tile once: fp32 -> bf16 [24c][16b][8i] ----
    {
        const float4* x4 = (const float4*)x;
        #pragma unroll
        for (int it = 0; it < 3; ++it) {
            int f = tid + BLOCK * it;          // < 768 float4
            int b2 = f / 48, r = f - b2 * 48;  // 48 float4 per b (24c*8i/4)
            float4 v = x4[(size_t)(gb0 + b2) * 2304 + c0 * 2 + r];
            int cp = r >> 1, i0 = (r & 1) * 4;
            *(uint2*)(xs + cp * 128 + b2 * 8 + i0) =
                make_uint2(pack2(v.x, v.y), pack2(v.z, v.w));
        }
    }

    const int ncnt = (wv < 2) ? 3 : 2;   // wave wv owns n = wv, wv+4, (wv+8)
    const float4* W4 = (const float4*)W;

    for (int p = 0; p < 3; ++p) {
        // ---- stage vsum tile from vg (written by previous reduce) ----
        if (p > 0) {
            #pragma unroll
            for (int it = 0; it < 3; ++it) {
                int f = tid + BLOCK * it;
                if (f < 640) {
                    int e = f * 4;
                    int b2 = e / 160, r = e - b2 * 160;
                    float4 v = *(const float4*)(vg + (size_t)(gb0 + b2) * 160 + r);
                    *(float4*)(vst + b2 * 164 + r) = v;
                }
            }
        }

        v4f sacc[3];
        sacc[0] = (v4f){0.f, 0.f, 0.f, 0.f};
        sacc[1] = (v4f){0.f, 0.f, 0.f, 0.f};
        sacc[2] = (v4f){0.f, 0.f, 0.f, 0.f};

        for (int st = 0; st < N_STAGES; ++st) {
            __syncthreads();   // prev sweep2/drain done with Ws; vst staged
            // ---- stage W round: 6 c's fp32 -> bf16 (1920 float4) ----
            #pragma unroll
            for (int it = 0; it < 8; ++it) {
                int f = tid + BLOCK * it;
                if (f < 1920) {
                    int n = f / 192, rr = f - n * 192;
                    int c = rr >> 5, k4 = rr & 31;
                    float4 v = W4[(size_t)n * 36864 +
                                  (size_t)(c0 + st * STAGE_C + c) * 32 + k4];
                    *(uint2*)(Ws + c * 1280 + n * 128 + k4 * 4) =
                        make_uint2(pack2(v.x, v.y), pack2(v.z, v.w));
                }
            }
            __syncthreads();

            if (p > 0) {
                // ---- sweep1: 15 independent (c,n) chains per wave ----
                #pragma unroll
                for (int k = 0; k < 15; ++k) {
                    const int idx = wv + 4 * k;      // < 60
                    const int c   = idx / 10;
                    const int n   = idx - c * 10;
                    v8s wa = {0, 0, 0, 0, 0, 0, 0, 0};
                    if (quad == 0)
                        wa = *(const v8s*)(Ws + c * 1280 + n * 128 + b * 8);
                    const v8s xb = *(const v8s*)(xs + (st * STAGE_C + c) * 128 + b * 8);
                    v4f u = __builtin_amdgcn_mfma_f32_16x16x32_bf16(
                        wa, xb, (v4f){0.f, 0.f, 0.f, 0.f}, 0, 0, 0);
                    const float4 v4 = *(const float4*)(vst + b * 164 + n * 16 + quad * 4);
                    float l = u[0] * v4.x + u[1] * v4.y + u[2] * v4.z + u[3] * v4.w;
                    l += __shfl_xor(l, 16);
                    l += __shfl_xor(l, 32);
                    const float e1 = __expf(l);      // |l| <~ 3: no max-sub needed
                    if (quad == 0) cfl[c * 163 + n * 16 + b] = e1;
                }
                __syncthreads();
                // ---- Z-step: 96 (c,b) sums ----
                if (tid < 96) {
                    const int c = tid >> 4, bb = tid & 15;
                    float Z = 0.f;
                    #pragma unroll
                    for (int n = 0; n < N_N; ++n) Z += cfl[c * 163 + n * 16 + bb];
                    rz[c * 16 + bb] = __builtin_amdgcn_rcpf(Z);
                }
                __syncthreads();
            }

            // ---- sweep2 ----
            #pragma unroll
            for (int Q = 0; Q < 2; ++Q) {
                const int  clq   = Q * 4 + quad;
                const bool valid = (clq < STAGE_C);
                const int  clql  = valid ? clq : 0;
                const v8s xq = *(const v8s*)(xs + (st * STAGE_C + clql) * 128 + b * 8);
                float xf[8];
                #pragma unroll
                for (int j = 0; j < 8; ++j) xf[j] = bf2f(xq[j]);
                #pragma unroll
                for (int jj = 0; jj < 3; ++jj) {
                    if (jj < ncnt) {
                        const int n = wv + 4 * jj;
                        const float cv = (p == 0) ? 0.1f
                            : cfl[clql * 163 + n * 16 + b] * rz[clql * 16 + b];
                        union { v8s s; uint32_t u[4]; } zu;
                        zu.u[0] = pack2(cv * xf[0], cv * xf[1]);
                        zu.u[1] = pack2(cv * xf[2], cv * xf[3]);
                        zu.u[2] = pack2(cv * xf[4], cv * xf[5]);
                        zu.u[3] = pack2(cv * xf[6], cv * xf[7]);
                        v8s wa = {0, 0, 0, 0, 0, 0, 0, 0};
                        if (valid)
                            wa = *(const v8s*)(Ws + clql * 1280 + n * 128 + b * 8);
                        sacc[jj] = __builtin_amdgcn_mfma_f32_16x16x32_bf16(
                            wa, zu.s, sacc[jj], 0, 0, 0);
                    }
                }
            }
        }

        __syncthreads();   // all Ws/xs/cfl reads done -> comb alias safe
        #pragma unroll
        for (int jj = 0; jj < 3; ++jj) {
            if (jj < ncnt) {
                const int n = wv + 4 * jj;
                #pragma unroll
                for (int r = 0; r < 4; ++r)
                    comb[b * 164 + n * 16 + quad * 4 + r] = sacc[jj][r];
            }
        }
        __syncthreads();
        // ---- drain partial s -> ps[chunk][b][160] ----
        #pragma unroll
        for (int it = 0; it < 3; ++it) {
            int f = tid + BLOCK * it;
            if (f < 640) {
                int e = f * 4;
                int bb = e / 160, rem = e - bb * 160;
                float4 v = *(const float4*)(comb + bb * 164 + rem);
                *(float4*)(&ps[((size_t)chunk * B_N + gb0 + bb) * 160 + rem]) = v;
            }
        }

        gridbar(bar, 2 * p);   // ps complete grid-wide

        // ---- reduce + squash: blocks flat<160, wave per group g = flat*4+wv ----
        if (flat < 160) {
            const int g  = flat * 4 + wv;       // 0..639; 4 groups per block? NO:
            // 160 blocks x 4 waves = 640 wave-slots; each handles 4 groups (2560 total)
            const int q  = lane & 3;
            const int h  = lane >> 2;
            #pragma unroll
            for (int rep = 0; rep < 4; ++rep) {
                const int gg = g + rep * 640;   // 0..2559 == b*10+n
                const int bb = gg / 10, n = gg - bb * 10;
                float4 s = make_float4(0.f, 0.f, 0.f, 0.f);
                #pragma unroll
                for (int m = 0; m < 3; ++m) {   // 48 chunks = 16 h-slices x 3
                    const int cc = h + 16 * m;
                    float4 v = *(const float4*)(
                        &ps[((size_t)cc * B_N + bb) * 160 + n * 16 + q * 4]);
                    s.x += v.x; s.y += v.y; s.z += v.z; s.w += v.w;
                }
                #pragma unroll
                for (int off = 4; off < 64; off <<= 1) {
                    s.x += __shfl_xor(s.x, off);
                    s.y += __shfl_xor(s.y, off);
                    s.z += __shfl_xor(s.z, off);
                    s.w += __shfl_xor(s.w, off);
                }
                float sq = s.x * s.x + s.y * s.y + s.z * s.z + s.w * s.w;
                sq += __shfl_xor(sq, 1);
                sq += __shfl_xor(sq, 2);
                const float scale = (sq / (1.f + sq)) / (sqrtf(sq) + 1e-8f);
                const float4 v = make_float4(scale * s.x, scale * s.y,
                                             scale * s.z, scale * s.w);
                if (h == 0) {
                    if (p == 2) {
                        *(float4*)(&out[(size_t)gg * D_N + q * 4]) = v;
                    } else {
                        float* vp = vg + (size_t)bb * 160 + n * 16 + q * 4;
                        if (p == 0) {
                            *(float4*)vp = v;
                        } else {
                            float4 o = *(const float4*)vp;
                            *(float4*)vp = make_float4(o.x + v.x, o.y + v.y,
                                                       o.z + v.z, o.w + v.w);
                        }
                    }
                }
            }
        }

        if (p < 2) gridbar(bar, 2 * p + 1);   // vg visible before next pass
    }
}

extern "C" void kernel_launch(void* const* d_in, const int* in_sizes, int n_in,
                              void* d_out, int out_size, void* d_ws, size_t ws_size,
                              hipStream_t stream)
{
    const float* x = (const float*)d_in[0];
    const float* W = (const float*)d_in[1];
    float* out = (float*)d_out;

    uint32_t* bar = (uint32_t*)d_ws;                     // 8 counters (zeroed below)
    float* vg = (float*)d_ws + 64;                       // [256][160] vsum accumulator
    float* ps = vg + (size_t)B_N * 160;                  // [48][256][160] partial s

    hipMemsetAsync(bar, 0, 256, stream);                 // capture-safe barrier init
    fused_routing<<<dim3(C_CHUNKS, 16), dim3(BLOCK), 0, stream>>>(
        x, W, bar, vg, ps, out);
}